// Round 3
// baseline (46.118 us; speedup 1.0000x reference)
//
#include <hip/hip_runtime.h>

// EtaWeights: out[i] = loss[i] > eta ? loss[i]*mask*eta : -loss[i]/eta + 1
// Pure elementwise streaming kernel: 128 MB in + 128 MB out, HBM-bound.
// R2: native ext_vector float4 (builtin-compatible) + nt stores + 4x MLP unroll.

typedef float vfloat4 __attribute__((ext_vector_type(4)));

__global__ __launch_bounds__(256) void EtaWeights_kernel(
    const vfloat4* __restrict__ in4,
    const float* __restrict__ eta_p,
    const float* __restrict__ mask_p,
    vfloat4* __restrict__ out4,
    int n4)
{
    const float eta     = eta_p[0];
    const float me      = mask_p[0] * eta;   // multiplier for the ">" branch
    const float inv_eta = 1.0f / eta;        // eta=0.5 -> exact 2.0

    const int stride  = gridDim.x * blockDim.x;   // float4 elements per step
    const int stride4 = stride * 4;               // per unrolled super-step
    int i = blockIdx.x * blockDim.x + threadIdx.x;

    #define APPLY(r, v)                                                      \
        r[0] = (v[0] > eta) ? v[0] * me : fmaf(-v[0], inv_eta, 1.0f);        \
        r[1] = (v[1] > eta) ? v[1] * me : fmaf(-v[1], inv_eta, 1.0f);        \
        r[2] = (v[2] > eta) ? v[2] * me : fmaf(-v[2], inv_eta, 1.0f);        \
        r[3] = (v[3] > eta) ? v[3] * me : fmaf(-v[3], inv_eta, 1.0f)

    // Main unrolled loop: 4 independent loads in flight per wave.
    for (; i + 3 * stride < n4; i += stride4) {
        vfloat4 v0 = in4[i];
        vfloat4 v1 = in4[i + stride];
        vfloat4 v2 = in4[i + 2 * stride];
        vfloat4 v3 = in4[i + 3 * stride];

        vfloat4 r0, r1, r2, r3;
        APPLY(r0, v0);
        APPLY(r1, v1);
        APPLY(r2, v2);
        APPLY(r3, v3);

        __builtin_nontemporal_store(r0, &out4[i]);
        __builtin_nontemporal_store(r1, &out4[i + stride]);
        __builtin_nontemporal_store(r2, &out4[i + 2 * stride]);
        __builtin_nontemporal_store(r3, &out4[i + 3 * stride]);
    }
    // Tail (not taken for N=2^25 with 2048x256 grid, kept for generality).
    for (; i < n4; i += stride) {
        vfloat4 v = in4[i];
        vfloat4 r;
        APPLY(r, v);
        __builtin_nontemporal_store(r, &out4[i]);
    }
    #undef APPLY
}

extern "C" void kernel_launch(void* const* d_in, const int* in_sizes, int n_in,
                              void* d_out, int out_size, void* d_ws, size_t ws_size,
                              hipStream_t stream) {
    const float* loss = (const float*)d_in[0];
    const float* eta  = (const float*)d_in[1];
    const float* mask = (const float*)d_in[2];
    float* out = (float*)d_out;

    const int n  = in_sizes[0];     // 33554432, divisible by 4
    const int n4 = n / 4;           // 8388608 float4 elements

    const int block = 256;
    // 2048 blocks = 256 CUs x 8 blocks/CU; each thread does 16 float4s
    // (4 super-steps x 4 unroll).
    int grid = (n4 + block - 1) / block;
    if (grid > 2048) grid = 2048;

    EtaWeights_kernel<<<grid, block, 0, stream>>>(
        (const vfloat4*)loss, eta, mask, (vfloat4*)out, n4);
}

// Round 4
// 45.949 us; speedup vs baseline: 1.0037x; 1.0037x over previous
//
#include <hip/hip_runtime.h>

// EtaWeights: out[i] = loss[i] > eta ? loss[i]*mask*eta : -loss[i]/eta + 1
// Pure elementwise streaming kernel: 128 MB in + 128 MB out, HBM-bound.
// R3: exact R0 structure (best so far, 45.35us) + nontemporal stores ONLY.
//     Goal: keep the zero-reuse output stream from evicting the L3-resident
//     input (R2 counters showed FETCH = 64 MB = half-input steady state).

typedef float vfloat4 __attribute__((ext_vector_type(4)));

__global__ __launch_bounds__(256) void EtaWeights_kernel(
    const vfloat4* __restrict__ in4,
    const float* __restrict__ eta_p,
    const float* __restrict__ mask_p,
    vfloat4* __restrict__ out4,
    int n4)
{
    const float eta     = eta_p[0];
    const float me      = mask_p[0] * eta;   // multiplier for the ">" branch
    const float inv_eta = 1.0f / eta;        // eta=0.5 -> exact 2.0

    const int stride = gridDim.x * blockDim.x;
    for (int i = blockIdx.x * blockDim.x + threadIdx.x; i < n4; i += stride) {
        vfloat4 v = in4[i];
        vfloat4 r;
        r[0] = (v[0] > eta) ? v[0] * me : fmaf(-v[0], inv_eta, 1.0f);
        r[1] = (v[1] > eta) ? v[1] * me : fmaf(-v[1], inv_eta, 1.0f);
        r[2] = (v[2] > eta) ? v[2] * me : fmaf(-v[2], inv_eta, 1.0f);
        r[3] = (v[3] > eta) ? v[3] * me : fmaf(-v[3], inv_eta, 1.0f);
        __builtin_nontemporal_store(r, &out4[i]);
    }
}

extern "C" void kernel_launch(void* const* d_in, const int* in_sizes, int n_in,
                              void* d_out, int out_size, void* d_ws, size_t ws_size,
                              hipStream_t stream) {
    const float* loss = (const float*)d_in[0];
    const float* eta  = (const float*)d_in[1];
    const float* mask = (const float*)d_in[2];
    float* out = (float*)d_out;

    const int n  = in_sizes[0];     // 33554432, divisible by 4
    const int n4 = n / 4;           // 8388608 float4 elements

    const int block = 256;
    // 2048 blocks = 256 CUs x 8 blocks/CU (32 waves/CU); grid-stride x16.
    int grid = (n4 + block - 1) / block;
    if (grid > 2048) grid = 2048;

    EtaWeights_kernel<<<grid, block, 0, stream>>>(
        (const vfloat4*)loss, eta, mask, (vfloat4*)out, n4);
}

// Round 5
// 42.237 us; speedup vs baseline: 1.0919x; 1.0879x over previous
//
#include <hip/hip_runtime.h>

// EtaWeights: out[i] = loss[i] > eta ? loss[i]*mask*eta : -loss[i]/eta + 1
// Pure elementwise streaming kernel: 128 MB in + 128 MB out, HBM-bound.
// R4: one-shot full grid (no grid-stride loop) — 32768 blocks x 256 thr,
//     one float4 per thread, contiguous 16KB per block. Plain stores
//     (nt proved neutral in R3). Single-variable test of dispatch shape.

typedef float vfloat4 __attribute__((ext_vector_type(4)));

__global__ __launch_bounds__(256) void EtaWeights_kernel(
    const vfloat4* __restrict__ in4,
    const float* __restrict__ eta_p,
    const float* __restrict__ mask_p,
    vfloat4* __restrict__ out4,
    int n4)
{
    const int i = blockIdx.x * blockDim.x + threadIdx.x;
    if (i >= n4) return;

    const float eta     = eta_p[0];
    const float me      = mask_p[0] * eta;   // multiplier for the ">" branch
    const float inv_eta = 1.0f / eta;        // eta=0.5 -> exact 2.0

    vfloat4 v = in4[i];
    vfloat4 r;
    r[0] = (v[0] > eta) ? v[0] * me : fmaf(-v[0], inv_eta, 1.0f);
    r[1] = (v[1] > eta) ? v[1] * me : fmaf(-v[1], inv_eta, 1.0f);
    r[2] = (v[2] > eta) ? v[2] * me : fmaf(-v[2], inv_eta, 1.0f);
    r[3] = (v[3] > eta) ? v[3] * me : fmaf(-v[3], inv_eta, 1.0f);
    out4[i] = r;
}

extern "C" void kernel_launch(void* const* d_in, const int* in_sizes, int n_in,
                              void* d_out, int out_size, void* d_ws, size_t ws_size,
                              hipStream_t stream) {
    const float* loss = (const float*)d_in[0];
    const float* eta  = (const float*)d_in[1];
    const float* mask = (const float*)d_in[2];
    float* out = (float*)d_out;

    const int n  = in_sizes[0];     // 33554432, divisible by 4
    const int n4 = n / 4;           // 8388608 float4 elements

    const int block = 256;
    const int grid  = (n4 + block - 1) / block;   // 32768 blocks, exact

    EtaWeights_kernel<<<grid, block, 0, stream>>>(
        (const vfloat4*)loss, eta, mask, (vfloat4*)out, n4);
}